// Round 1
// baseline (735.095 us; speedup 1.0000x reference)
//
#include <hip/hip_runtime.h>
#include <math.h>

#define BB 16
#define CC 128
#define TT 1024
#define KK 7
#define DK 64

// ---------------- pos encoding + add ----------------
__global__ __launch_bounds__(256) void k_addpos(const float* __restrict__ x,
                                                float* __restrict__ out) {
  int bc = blockIdx.x;          // b*CC + c
  int c = bc & (CC - 1);
  float ce = (float)(c & ~1);
  float freq = expf(-(ce / (float)CC) * 9.210340371976184f); // ln(10000)
  float phase = (c & 1) ? 1.5707963267948966f : 0.0f;
  const float* xr = x + (size_t)bc * TT;
  float* orow = out + (size_t)bc * TT;
  for (int t = threadIdx.x; t < TT; t += 256) {
    orow[t] = xr[t] + sinf((float)t * freq + phase);
  }
}

// ---------------- layernorm (3 kernels) ----------------
__global__ __launch_bounds__(256) void k_ln_part(const float* __restrict__ x,
                                                 float* __restrict__ part) {
  int b = blockIdx.x >> 6;
  int blk = blockIdx.x & 63;
  const int CHUNK = CC * TT / 64;  // 2048
  const float4* xb = (const float4*)(x + (size_t)b * CC * TT + (size_t)blk * CHUNK);
  float s = 0.f, ss = 0.f;
  for (int i = threadIdx.x; i < CHUNK / 4; i += 256) {
    float4 v = xb[i];
    s += v.x + v.y + v.z + v.w;
    ss += v.x * v.x + v.y * v.y + v.z * v.z + v.w * v.w;
  }
#pragma unroll
  for (int off = 32; off; off >>= 1) {
    s += __shfl_xor(s, off);
    ss += __shfl_xor(ss, off);
  }
  __shared__ float sh[8];
  int w = threadIdx.x >> 6;
  if ((threadIdx.x & 63) == 0) { sh[w * 2] = s; sh[w * 2 + 1] = ss; }
  __syncthreads();
  if (threadIdx.x == 0) {
    for (int i = 1; i < 4; ++i) { s += sh[i * 2]; ss += sh[i * 2 + 1]; }
    part[blockIdx.x * 2] = s;
    part[blockIdx.x * 2 + 1] = ss;
  }
}

__global__ void k_ln_final(const float* __restrict__ part, float* __restrict__ stats) {
  int b = blockIdx.x;
  int t = threadIdx.x;  // 64 threads
  float s = part[(b * 64 + t) * 2];
  float ss = part[(b * 64 + t) * 2 + 1];
#pragma unroll
  for (int off = 32; off; off >>= 1) {
    s += __shfl_xor(s, off);
    ss += __shfl_xor(ss, off);
  }
  if (t == 0) {
    float inv = 1.f / (float)(CC * TT);
    float mu = s * inv;
    float var = ss * inv - mu * mu;
    stats[b * 2] = mu;
    stats[b * 2 + 1] = rsqrtf(var + 1e-5f);
  }
}

__global__ __launch_bounds__(256) void k_ln_apply(const float* __restrict__ x,
                                                  const float* __restrict__ g,
                                                  const float* __restrict__ be,
                                                  const float* __restrict__ stats,
                                                  float* __restrict__ out) {
  int i = blockIdx.x * 256 + threadIdx.x;  // float4 index over BB*CC*TT/4
  int b = i >> 15;                          // / (CC*TT/4)
  int ct4 = i & 32767;
  float mu = stats[b * 2], rs = stats[b * 2 + 1];
  float4 xv = ((const float4*)x)[i];
  float4 gv = ((const float4*)g)[ct4];
  float4 bv = ((const float4*)be)[ct4];
  float4 o;
  o.x = (xv.x - mu) * rs * gv.x + bv.x;
  o.y = (xv.y - mu) * rs * gv.y + bv.y;
  o.z = (xv.z - mu) * rs * gv.z + bv.z;
  o.w = (xv.w - mu) * rs * gv.w + bv.w;
  ((float4*)out)[i] = o;
}

// ---------------- fused dsconv: depthwise + pointwise + relu + residual ----------------
__global__ __launch_bounds__(256) void k_dsconv(const float* __restrict__ in,
                                                const float* __restrict__ res,
                                                const float* __restrict__ dww,
                                                const float* __restrict__ dwb,
                                                const float* __restrict__ pww,
                                                const float* __restrict__ pwb,
                                                float* __restrict__ out) {
  const int TW = 32;
  int tile = blockIdx.x & 31;
  int b = blockIdx.x >> 5;
  int t0 = tile * TW;
  __shared__ float xs[CC][TW + 6];
  __shared__ float ds[CC][TW + 1];
  for (int i = threadIdx.x; i < CC * (TW + 6); i += 256) {
    int c = i / (TW + 6), j = i % (TW + 6);
    int t = t0 + j - 3;
    xs[c][j] = (t >= 0 && t < TT) ? in[((size_t)b * CC + c) * TT + t] : 0.f;
  }
  __syncthreads();
  for (int i = threadIdx.x; i < CC * TW; i += 256) {
    int c = i >> 5, t = i & 31;
    float acc = dwb[c];
#pragma unroll
    for (int j = 0; j < KK; ++j) acc += dww[c * KK + j] * xs[c][t + j];
    ds[c][t] = acc;
  }
  __syncthreads();
  int t = threadIdx.x & 31;
  int og = threadIdx.x >> 5;  // 8 groups of 16 output channels
  float acc[16];
#pragma unroll
  for (int j = 0; j < 16; ++j) acc[j] = pwb[og * 16 + j];
  for (int c = 0; c < CC; ++c) {
    float dv = ds[c][t];
#pragma unroll
    for (int j = 0; j < 16; ++j) acc[j] += pww[(og * 16 + j) * CC + c] * dv;
  }
#pragma unroll
  for (int j = 0; j < 16; ++j) {
    size_t idx = ((size_t)b * CC + og * 16 + j) * TT + t0 + t;
    float vv = acc[j];
    vv = vv > 0.f ? vv : 0.f;
    out[idx] = vv + res[idx];
  }
}

// ---------------- q,k,v projections ----------------
__global__ __launch_bounds__(256) void k_qkv(const float* __restrict__ in,
                                             const float* __restrict__ Wq,
                                             const float* __restrict__ Wk,
                                             const float* __restrict__ Wv,
                                             float* __restrict__ q,
                                             float* __restrict__ k,
                                             float* __restrict__ v) {
  const int TW = 32;
  int tile = blockIdx.x & 31, b = blockIdx.x >> 5;
  int t0 = tile * TW;
  __shared__ float xs[CC][TW + 1];
  for (int i = threadIdx.x; i < CC * TW; i += 256) {
    int c = i >> 5, t = i & 31;
    xs[c][t] = in[((size_t)b * CC + c) * TT + t0 + t];
  }
  __syncthreads();
  int t = threadIdx.x & 31, dg = threadIdx.x >> 5;  // 8 dim-groups of 8
  float aq[8], ak[8], av[8];
#pragma unroll
  for (int j = 0; j < 8; ++j) { aq[j] = 0.f; ak[j] = 0.f; av[j] = 0.f; }
  for (int c = 0; c < CC; ++c) {
    float xv = xs[c][t];
#pragma unroll
    for (int j = 0; j < 8; ++j) {
      int d = dg * 8 + j;
      aq[j] += Wq[c * DK + d] * xv;
      ak[j] += Wk[c * DK + d] * xv;
      av[j] += Wv[c * DK + d] * xv;
    }
  }
  size_t base = ((size_t)b * TT + t0 + t) * DK + dg * 8;
#pragma unroll
  for (int j = 0; j < 8; ++j) {
    q[base + j] = aq[j];
    k[base + j] = ak[j];
    v[base + j] = av[j];
  }
}

// ---------------- flash attention (single head, d=64) ----------------
__global__ __launch_bounds__(256) void k_attn(const float* __restrict__ q,
                                              const float* __restrict__ kk,
                                              const float* __restrict__ vv,
                                              const float* __restrict__ mask,
                                              float* __restrict__ head) {
  int tile = blockIdx.x & 31;
  int b = blockIdx.x >> 5;
  int r = threadIdx.x >> 3;   // local q row 0..31
  int sub = threadIdx.x & 7;  // 0..7
  int qrow = tile * 32 + r;

  __shared__ float qs[32][68];
  __shared__ float ks[64][68];
  __shared__ float vs[64][68];
  __shared__ float ps[32][68];
  __shared__ float ms[64];

  for (int i = threadIdx.x; i < 32 * 16; i += 256) {
    int rr = i >> 4, d4 = i & 15;
    float4 val = ((const float4*)(q + ((size_t)b * TT + tile * 32 + rr) * DK))[d4];
    *(float4*)&qs[rr][d4 * 4] = val;
  }

  float m = -INFINITY, l = 0.f;
  float acc[8];
#pragma unroll
  for (int j = 0; j < 8; ++j) acc[j] = 0.f;
  const float scale = 0.125f;  // 1/sqrt(64)

  for (int kb = 0; kb < TT / 64; ++kb) {
    __syncthreads();  // protect ks/vs/ps from previous iteration readers
    for (int i = threadIdx.x; i < 64 * 16; i += 256) {
      int kl = i >> 4, d4 = i & 15;
      size_t gb = ((size_t)b * TT + kb * 64 + kl) * DK;
      *(float4*)&ks[kl][d4 * 4] = ((const float4*)(kk + gb))[d4];
      *(float4*)&vs[kl][d4 * 4] = ((const float4*)(vv + gb))[d4];
    }
    if (threadIdx.x < 64) ms[threadIdx.x] = mask[(size_t)b * TT + kb * 64 + threadIdx.x];
    __syncthreads();

    float sc[8];
#pragma unroll
    for (int jj = 0; jj < 8; ++jj) sc[jj] = 0.f;
    for (int d4 = 0; d4 < 16; ++d4) {
      float4 qv = *(const float4*)&qs[r][d4 * 4];
#pragma unroll
      for (int jj = 0; jj < 8; ++jj) {
        int kl = jj * 8 + sub;  // strided: consecutive subs -> consecutive rows (bank-clean)
        float4 kv = *(const float4*)&ks[kl][d4 * 4];
        sc[jj] += qv.x * kv.x + qv.y * kv.y + qv.z * kv.z + qv.w * kv.w;
      }
    }
    float tmax = -INFINITY;
#pragma unroll
    for (int jj = 0; jj < 8; ++jj) {
      int kl = jj * 8 + sub;
      float mv = ms[kl];
      sc[jj] = sc[jj] * scale * mv + (1.f - mv) * (-1e30f);
      tmax = fmaxf(tmax, sc[jj]);
    }
#pragma unroll
    for (int off = 1; off < 8; off <<= 1) tmax = fmaxf(tmax, __shfl_xor(tmax, off));
    float mnew = fmaxf(m, tmax);
    float alpha = expf(m - mnew);
    float psum = 0.f;
#pragma unroll
    for (int jj = 0; jj < 8; ++jj) {
      float p = expf(sc[jj] - mnew);
      ps[r][jj * 8 + sub] = p;
      psum += p;
    }
#pragma unroll
    for (int off = 1; off < 8; off <<= 1) psum += __shfl_xor(psum, off);
    l = l * alpha + psum;
    m = mnew;
    __syncthreads();  // ps visible to whole row group

#pragma unroll
    for (int j = 0; j < 8; ++j) acc[j] *= alpha;
    for (int kl = 0; kl < 64; ++kl) {
      float p = ps[r][kl];
      float4 v0 = *(const float4*)&vs[kl][sub * 8];
      float4 v1 = *(const float4*)&vs[kl][sub * 8 + 4];
      acc[0] += p * v0.x; acc[1] += p * v0.y; acc[2] += p * v0.z; acc[3] += p * v0.w;
      acc[4] += p * v1.x; acc[5] += p * v1.y; acc[6] += p * v1.z; acc[7] += p * v1.w;
    }
  }

  float qmv = mask[(size_t)b * TT + qrow];
  float invl = qmv / l;  // l >= 1 always (p=1 at the max)
  float4 o0, o1;
  o0.x = acc[0] * invl; o0.y = acc[1] * invl; o0.z = acc[2] * invl; o0.w = acc[3] * invl;
  o1.x = acc[4] * invl; o1.y = acc[5] * invl; o1.z = acc[6] * invl; o1.w = acc[7] * invl;
  size_t hb = ((size_t)b * TT + qrow) * DK + sub * 8;
  *(float4*)(head + hb) = o0;
  *(float4*)(head + hb + 4) = o1;
}

// ---------------- heads@Wo (tiled heads folded) + residual ----------------
__global__ __launch_bounds__(256) void k_attnout(const float* __restrict__ head,
                                                 const float* __restrict__ Wo,
                                                 const float* __restrict__ res,
                                                 float* __restrict__ out) {
  const int TW = 32;
  int tile = blockIdx.x & 31, b = blockIdx.x >> 5;
  int t0 = tile * TW;
  __shared__ float hs[TW][65];
  __shared__ float wo2[DK][CC];  // Wo[d] + Wo[d+64]
  for (int i = threadIdx.x; i < TW * DK; i += 256) {
    int t = i >> 6, d = i & 63;
    hs[t][d] = head[((size_t)b * TT + t0 + t) * DK + d];
  }
  for (int i = threadIdx.x; i < DK * CC / 4; i += 256) {
    int d = i >> 5, o4 = i & 31;
    float4 a = ((const float4*)(Wo + d * CC))[o4];
    float4 bq = ((const float4*)(Wo + (d + 64) * CC))[o4];
    a.x += bq.x; a.y += bq.y; a.z += bq.z; a.w += bq.w;
    *(float4*)&wo2[d][o4 * 4] = a;
  }
  __syncthreads();
  int t = threadIdx.x & 31, og = threadIdx.x >> 5;
  float acc[16];
#pragma unroll
  for (int j = 0; j < 16; ++j) acc[j] = 0.f;
  for (int d = 0; d < DK; ++d) {
    float hv = hs[t][d];
#pragma unroll
    for (int j = 0; j < 16; ++j) acc[j] += wo2[d][og * 16 + j] * hv;
  }
#pragma unroll
  for (int j = 0; j < 16; ++j) {
    size_t idx = ((size_t)b * CC + og * 16 + j) * TT + t0 + t;
    out[idx] = acc[j] + res[idx];
  }
}

// ---------------- FC + relu + residual -> final output ----------------
__global__ __launch_bounds__(256) void k_fc(const float* __restrict__ in,
                                            const float* __restrict__ fw,
                                            const float* __restrict__ fb,
                                            const float* __restrict__ res,
                                            float* __restrict__ out) {
  const int TW = 32;
  int tile = blockIdx.x & 31, b = blockIdx.x >> 5;
  int t0 = tile * TW;
  __shared__ float xs[CC][TW + 1];
  for (int i = threadIdx.x; i < CC * TW; i += 256) {
    int c = i >> 5, t = i & 31;
    xs[c][t] = in[((size_t)b * CC + c) * TT + t0 + t];
  }
  __syncthreads();
  int t = threadIdx.x & 31, og = threadIdx.x >> 5;
  float acc[16];
#pragma unroll
  for (int j = 0; j < 16; ++j) acc[j] = fb[og * 16 + j];
  for (int c = 0; c < CC; ++c) {
    float xv = xs[c][t];
#pragma unroll
    for (int j = 0; j < 16; ++j) acc[j] += fw[(og * 16 + j) * CC + c] * xv;
  }
#pragma unroll
  for (int j = 0; j < 16; ++j) {
    size_t idx = ((size_t)b * CC + og * 16 + j) * TT + t0 + t;
    float vv = acc[j];
    vv = vv > 0.f ? vv : 0.f;
    out[idx] = vv + res[idx];
  }
}

extern "C" void kernel_launch(void* const* d_in, const int* in_sizes, int n_in,
                              void* d_out, int out_size, void* d_ws, size_t ws_size,
                              hipStream_t stream) {
  const float* x    = (const float*)d_in[0];
  const float* mask = (const float*)d_in[1];
  const float* dww  = (const float*)d_in[2];
  const float* dwb  = (const float*)d_in[3];
  const float* pww  = (const float*)d_in[4];
  const float* pwb  = (const float*)d_in[5];
  const float* n0g  = (const float*)d_in[6];
  const float* n0b  = (const float*)d_in[7];
  const float* nsg  = (const float*)d_in[8];
  const float* nsb  = (const float*)d_in[9];
  const float* neg_ = (const float*)d_in[10];
  const float* neb  = (const float*)d_in[11];
  const float* Wq   = (const float*)d_in[12];
  const float* Wk   = (const float*)d_in[13];
  const float* Wv   = (const float*)d_in[14];
  const float* Wo   = (const float*)d_in[15];
  const float* fcw  = (const float*)d_in[16];
  const float* fcb  = (const float*)d_in[17];
  float* out = (float*)d_out;

  float* W = (float*)d_ws;
  const size_t NBCT = (size_t)BB * CC * TT;  // 2097152
  const size_t NBTD = (size_t)BB * TT * DK;  // 1048576
  float* O    = W;
  float* R    = W + NBCT;
  float* S    = W + 2 * NBCT;
  float* Q    = W + 3 * NBCT;
  float* Kb   = Q + NBTD;
  float* Vb   = Kb + NBTD;
  float* HD   = Vb + NBTD;
  float* PART = HD + NBTD;
  float* STAT = PART + BB * 64 * 2;

  auto ln = [&](const float* src, const float* g, const float* be, float* dst) {
    k_ln_part<<<BB * 64, 256, 0, stream>>>(src, PART);
    k_ln_final<<<BB, 64, 0, stream>>>(PART, STAT);
    k_ln_apply<<<(int)(NBCT / 4 / 256), 256, 0, stream>>>(src, g, be, STAT, dst);
  };

  k_addpos<<<BB * CC, 256, 0, stream>>>(x, O);
  ln(O, n0g, n0b, R);
  for (int i = 0; i < 4; ++i) {
    k_dsconv<<<BB * 32, 256, 0, stream>>>(O, R, dww + i * CC * KK, dwb + i * CC,
                                          pww + (size_t)i * CC * CC, pwb + i * CC, S);
    ln(S, nsg + (size_t)i * CC * TT, nsb + (size_t)i * CC * TT, O);
    float* tmp = R; R = S; S = tmp;
  }
  k_qkv<<<BB * 32, 256, 0, stream>>>(O, Wq, Wk, Wv, Q, Kb, Vb);
  k_attn<<<BB * 32, 256, 0, stream>>>(Q, Kb, Vb, mask, HD);
  k_attnout<<<BB * 32, 256, 0, stream>>>(HD, Wo, R, S);
  ln(S, neg_, neb, O);
  k_fc<<<BB * 32, 256, 0, stream>>>(O, fcw, fcb, S, out);
}

// Round 2
// 555.212 us; speedup vs baseline: 1.3240x; 1.3240x over previous
//
#include <hip/hip_runtime.h>
#include <math.h>

#define BB 16
#define CC 128
#define TT 1024
#define KK 7
#define DK 64

typedef float f32x4 __attribute__((ext_vector_type(4)));
typedef short s16x8 __attribute__((ext_vector_type(8)));

__device__ inline short f2bf(float f) {
  union { float f; unsigned u; } v; v.f = f;
  unsigned r = (v.u + 0x7FFFu + ((v.u >> 16) & 1u)) >> 16;
  return (short)r;
}

// block-wide (256 threads) reduce of (s,ss) -> dst[0..1]
__device__ inline void block_partial_256(float s, float ss, float* dst) {
#pragma unroll
  for (int off = 32; off; off >>= 1) { s += __shfl_xor(s, off); ss += __shfl_xor(ss, off); }
  __shared__ float red[8];
  int w = threadIdx.x >> 6;
  if ((threadIdx.x & 63) == 0) { red[2 * w] = s; red[2 * w + 1] = ss; }
  __syncthreads();
  if (threadIdx.x == 0) {
    for (int i = 1; i < 4; ++i) { s += red[2 * i]; ss += red[2 * i + 1]; }
    dst[0] = s; dst[1] = ss;
  }
}

// reduce n partial (sum,sumsq) pairs for one batch -> sh[0]=mu, sh[1]=rsqrt(var+eps)
__device__ inline void ln_stats_from_parts(const float* part_batch, int n, float* sh) {
  if (threadIdx.x < 64) {
    float s = 0.f, ss = 0.f;
    for (int i = threadIdx.x; i < n; i += 64) { s += part_batch[2 * i]; ss += part_batch[2 * i + 1]; }
#pragma unroll
    for (int off = 32; off; off >>= 1) { s += __shfl_xor(s, off); ss += __shfl_xor(ss, off); }
    if (threadIdx.x == 0) {
      const float invN = 1.f / (float)(CC * TT);
      float mu = s * invN;
      sh[0] = mu;
      sh[1] = rsqrtf(ss * invN - mu * mu + 1e-5f);
    }
  }
  __syncthreads();
}

// ---------------- pos encoding + add (+ LN partials) ----------------
__global__ __launch_bounds__(256) void k_addpos(const float* __restrict__ x,
                                                float* __restrict__ out,
                                                float* __restrict__ part) {
  int bc = blockIdx.x;  // b*CC + c
  int c = bc & (CC - 1);
  float ce = (float)(c & ~1);
  float freq = expf(-(ce / (float)CC) * 9.210340371976184f);
  float phase = (c & 1) ? 1.5707963267948966f : 0.0f;
  const float* xr = x + (size_t)bc * TT;
  float* orow = out + (size_t)bc * TT;
  float s = 0.f, ss = 0.f;
  for (int t = threadIdx.x; t < TT; t += 256) {
    float v = xr[t] + sinf((float)t * freq + phase);
    orow[t] = v;
    s += v; ss += v * v;
  }
  block_partial_256(s, ss, part + (size_t)bc * 2);
}

// ------- fused dsconv: [LN-in] depthwise + pointwise + relu + [LN-res] residual + partials -------
template <bool LN_IN, bool LN_RES>
__global__ __launch_bounds__(256) void k_dsconv(const float* __restrict__ in,
                                                const float* __restrict__ lng,
                                                const float* __restrict__ lnb,
                                                const float* __restrict__ part_in, int npart,
                                                const float* __restrict__ dww,
                                                const float* __restrict__ dwb,
                                                const float* __restrict__ pww,
                                                const float* __restrict__ pwb,
                                                float* __restrict__ out,
                                                float* __restrict__ part_out) {
  const int TW = 32;
  int tile = blockIdx.x & 31;
  int b = blockIdx.x >> 5;
  int t0 = tile * TW;
  __shared__ float stats[2];
  __shared__ float xs[CC][TW + 7];  // 38 used, stride 39 (odd)
  __shared__ float ds[CC][TW + 1];
  ln_stats_from_parts(part_in + (size_t)b * npart * 2, npart, stats);
  float mu = stats[0], rs = stats[1];

  for (int i = threadIdx.x; i < CC * 38; i += 256) {
    int c = i / 38, j = i % 38;
    int t = t0 + j - 3;
    float v = 0.f;
    if (t >= 0 && t < TT) {
      v = in[((size_t)b * CC + c) * TT + t];
      if (LN_IN) v = (v - mu) * rs * lng[c * TT + t] + lnb[c * TT + t];
    }
    xs[c][j] = v;
  }
  __syncthreads();
  for (int i = threadIdx.x; i < CC * TW; i += 256) {
    int c = i >> 5, t = i & 31;
    float acc = dwb[c];
#pragma unroll
    for (int j = 0; j < KK; ++j) acc += dww[c * KK + j] * xs[c][t + j];
    ds[c][t] = acc;
  }
  __syncthreads();
  int t = threadIdx.x & 31;
  int og = threadIdx.x >> 5;
  float acc[16];
#pragma unroll
  for (int j = 0; j < 16; ++j) acc[j] = pwb[og * 16 + j];
  for (int c = 0; c < CC; ++c) {
    float dv = ds[c][t];
#pragma unroll
    for (int j = 0; j < 16; ++j) acc[j] += pww[(og * 16 + j) * CC + c] * dv;
  }
  float s = 0.f, ss = 0.f;
#pragma unroll
  for (int j = 0; j < 16; ++j) {
    int co = og * 16 + j;
    size_t idx = ((size_t)b * CC + co) * TT + t0 + t;
    float rv = in[idx];
    if (LN_RES) rv = (rv - mu) * rs * lng[co * TT + t0 + t] + lnb[co * TT + t0 + t];
    float o = (acc[j] > 0.f ? acc[j] : 0.f) + rv;
    out[idx] = o;
    s += o; ss += o * o;
  }
  block_partial_256(s, ss, part_out + (size_t)blockIdx.x * 2);
}

// ---------------- q,k,v projections (LN fused on input, bf16 out, V transposed) ----------------
__global__ __launch_bounds__(256) void k_qkv(const float* __restrict__ in,
                                             const float* __restrict__ lng,
                                             const float* __restrict__ lnb,
                                             const float* __restrict__ part_in,
                                             const float* __restrict__ Wq,
                                             const float* __restrict__ Wk,
                                             const float* __restrict__ Wv,
                                             short* __restrict__ q,
                                             short* __restrict__ k,
                                             short* __restrict__ vt) {
  const int TW = 32;
  int tile = blockIdx.x & 31, b = blockIdx.x >> 5;
  int t0 = tile * TW;
  __shared__ float stats[2];
  __shared__ float xs[CC][TW + 1];
  ln_stats_from_parts(part_in + (size_t)b * 32 * 2, 32, stats);
  float mu = stats[0], rs = stats[1];
  for (int i = threadIdx.x; i < CC * TW; i += 256) {
    int c = i >> 5, t = i & 31;
    float v = in[((size_t)b * CC + c) * TT + t0 + t];
    xs[c][t] = (v - mu) * rs * lng[c * TT + t0 + t] + lnb[c * TT + t0 + t];
  }
  __syncthreads();
  int t = threadIdx.x & 31, dg = threadIdx.x >> 5;
  float aq[8], ak[8], av[8];
#pragma unroll
  for (int j = 0; j < 8; ++j) { aq[j] = 0.f; ak[j] = 0.f; av[j] = 0.f; }
  for (int c = 0; c < CC; ++c) {
    float xv = xs[c][t];
#pragma unroll
    for (int j = 0; j < 8; ++j) {
      int d = dg * 8 + j;
      aq[j] += Wq[c * DK + d] * xv;
      ak[j] += Wk[c * DK + d] * xv;
      av[j] += Wv[c * DK + d] * xv;
    }
  }
  size_t base = ((size_t)b * TT + t0 + t) * DK + dg * 8;
  uint4 qo, ko;
  qo.x = (unsigned short)f2bf(aq[0]) | ((unsigned)(unsigned short)f2bf(aq[1]) << 16);
  qo.y = (unsigned short)f2bf(aq[2]) | ((unsigned)(unsigned short)f2bf(aq[3]) << 16);
  qo.z = (unsigned short)f2bf(aq[4]) | ((unsigned)(unsigned short)f2bf(aq[5]) << 16);
  qo.w = (unsigned short)f2bf(aq[6]) | ((unsigned)(unsigned short)f2bf(aq[7]) << 16);
  ko.x = (unsigned short)f2bf(ak[0]) | ((unsigned)(unsigned short)f2bf(ak[1]) << 16);
  ko.y = (unsigned short)f2bf(ak[2]) | ((unsigned)(unsigned short)f2bf(ak[3]) << 16);
  ko.z = (unsigned short)f2bf(ak[4]) | ((unsigned)(unsigned short)f2bf(ak[5]) << 16);
  ko.w = (unsigned short)f2bf(ak[6]) | ((unsigned)(unsigned short)f2bf(ak[7]) << 16);
  *(uint4*)(q + base) = qo;
  *(uint4*)(k + base) = ko;
#pragma unroll
  for (int j = 0; j < 8; ++j)
    vt[((size_t)b * DK + dg * 8 + j) * TT + t0 + t] = f2bf(av[j]);
}

// ---------------- flash attention, bf16 MFMA 16x16x32 ----------------
__global__ __launch_bounds__(256) void k_attn(const short* __restrict__ qb,
                                              const short* __restrict__ kbuf,
                                              const short* __restrict__ vtb,
                                              const float* __restrict__ mask,
                                              float* __restrict__ head) {
  int b = blockIdx.x >> 4, qt = blockIdx.x & 15;
  int w = threadIdx.x >> 6, lane = threadIdx.x & 63;
  int lo = lane & 15, hi = lane >> 4;

  __shared__ __align__(16) short ks[64][72];
  __shared__ __align__(16) short vt[64][72];
  __shared__ __align__(16) short ps[4][16][72];
  __shared__ float ms[64];

  const short* qp = qb + ((size_t)b * TT + qt * 64 + w * 16 + lo) * DK + hi * 8;
  s16x8 aq0 = *(const s16x8*)qp;
  s16x8 aq1 = *(const s16x8*)(qp + 32);

  f32x4 acc[4];
  float m_i[4], l_i[4];
#pragma unroll
  for (int r = 0; r < 4; ++r) {
    m_i[r] = -3.0e38f; l_i[r] = 0.f;
#pragma unroll
    for (int nt = 0; nt < 4; ++nt) acc[nt][r] = 0.f;
  }
  const float scale = 0.125f;  // 1/sqrt(64)

  for (int kb2 = 0; kb2 < TT / 64; ++kb2) {
    __syncthreads();
    for (int i = threadIdx.x; i < 512; i += 256) {
      int r = i >> 3, ch = i & 7;
      *(s16x8*)&ks[r][ch * 8] =
          *(const s16x8*)(kbuf + ((size_t)b * TT + kb2 * 64 + r) * DK + ch * 8);
      *(s16x8*)&vt[r][ch * 8] =
          *(const s16x8*)(vtb + ((size_t)b * DK + r) * TT + kb2 * 64 + ch * 8);
    }
    if (threadIdx.x < 64) ms[threadIdx.x] = mask[(size_t)b * TT + kb2 * 64 + threadIdx.x];
    __syncthreads();

    // S = Q K^T
    f32x4 sc[4];
#pragma unroll
    for (int nt = 0; nt < 4; ++nt) {
      f32x4 z; z[0] = 0.f; z[1] = 0.f; z[2] = 0.f; z[3] = 0.f;
      s16x8 bk0 = *(const s16x8*)&ks[nt * 16 + lo][hi * 8];
      s16x8 bk1 = *(const s16x8*)&ks[nt * 16 + lo][32 + hi * 8];
      z = __builtin_amdgcn_mfma_f32_16x16x32_bf16(aq0, bk0, z, 0, 0, 0);
      z = __builtin_amdgcn_mfma_f32_16x16x32_bf16(aq1, bk1, z, 0, 0, 0);
      sc[nt] = z;
    }
#pragma unroll
    for (int nt = 0; nt < 4; ++nt) {
      float mv = ms[nt * 16 + lo];
      float addv = (1.f - mv) * -1e30f;
#pragma unroll
      for (int r = 0; r < 4; ++r) sc[nt][r] = sc[nt][r] * scale * mv + addv;
    }
    // online softmax (C-layout: row = hi*4+r, col = nt*16+lo)
    float alpha[4], psum[4];
#pragma unroll
    for (int r = 0; r < 4; ++r) {
      float m0 = fmaxf(fmaxf(sc[0][r], sc[1][r]), fmaxf(sc[2][r], sc[3][r]));
#pragma unroll
      for (int off = 1; off < 16; off <<= 1) m0 = fmaxf(m0, __shfl_xor(m0, off));
      float mn = fmaxf(m_i[r], m0);
      alpha[r] = __expf(m_i[r] - mn);
      m_i[r] = mn;
      psum[r] = 0.f;
    }
#pragma unroll
    for (int nt = 0; nt < 4; ++nt) {
#pragma unroll
      for (int r = 0; r < 4; ++r) {
        float p = __expf(sc[nt][r] - m_i[r]);
        psum[r] += p;
        ps[w][hi * 4 + r][nt * 16 + lo] = f2bf(p);
      }
    }
#pragma unroll
    for (int r = 0; r < 4; ++r) {
      float sum = psum[r];
#pragma unroll
      for (int off = 1; off < 16; off <<= 1) sum += __shfl_xor(sum, off);
      l_i[r] = l_i[r] * alpha[r] + sum;
    }
#pragma unroll
    for (int nt = 0; nt < 4; ++nt)
#pragma unroll
      for (int r = 0; r < 4; ++r) acc[nt][r] *= alpha[r];

    // O += P V  (A-frags of P via wave-private LDS round-trip)
    s16x8 ap0 = *(const s16x8*)&ps[w][lo][hi * 8];
    s16x8 ap1 = *(const s16x8*)&ps[w][lo][32 + hi * 8];
#pragma unroll
    for (int nt = 0; nt < 4; ++nt) {
      s16x8 bv0 = *(const s16x8*)&vt[nt * 16 + lo][hi * 8];
      s16x8 bv1 = *(const s16x8*)&vt[nt * 16 + lo][32 + hi * 8];
      acc[nt] = __builtin_amdgcn_mfma_f32_16x16x32_bf16(ap0, bv0, acc[nt], 0, 0, 0);
      acc[nt] = __builtin_amdgcn_mfma_f32_16x16x32_bf16(ap1, bv1, acc[nt], 0, 0, 0);
    }
  }
#pragma unroll
  for (int r = 0; r < 4; ++r) {
    int row = qt * 64 + w * 16 + hi * 4 + r;
    float qm = mask[(size_t)b * TT + row];
    float inv = qm / l_i[r];
#pragma unroll
    for (int nt = 0; nt < 4; ++nt)
      head[((size_t)b * TT + row) * DK + nt * 16 + lo] = acc[nt][r] * inv;
  }
}

// ---------------- heads@Wo + residual (+ partials) ----------------
__global__ __launch_bounds__(256) void k_attnout(const float* __restrict__ head,
                                                 const float* __restrict__ Wo,
                                                 const float* __restrict__ res,
                                                 float* __restrict__ out,
                                                 float* __restrict__ part_out) {
  const int TW = 32;
  int tile = blockIdx.x & 31, b = blockIdx.x >> 5;
  int t0 = tile * TW;
  __shared__ float hs[TW][65];
  __shared__ float wo2[DK][CC];
  for (int i = threadIdx.x; i < TW * DK; i += 256) {
    int t = i >> 6, d = i & 63;
    hs[t][d] = head[((size_t)b * TT + t0 + t) * DK + d];
  }
  for (int i = threadIdx.x; i < DK * CC / 4; i += 256) {
    int d = i >> 5, o4 = i & 31;
    float4 a = ((const float4*)(Wo + d * CC))[o4];
    float4 bq = ((const float4*)(Wo + (d + 64) * CC))[o4];
    a.x += bq.x; a.y += bq.y; a.z += bq.z; a.w += bq.w;
    *(float4*)&wo2[d][o4 * 4] = a;
  }
  __syncthreads();
  int t = threadIdx.x & 31, og = threadIdx.x >> 5;
  float acc[16];
#pragma unroll
  for (int j = 0; j < 16; ++j) acc[j] = 0.f;
  for (int d = 0; d < DK; ++d) {
    float hv = hs[t][d];
#pragma unroll
    for (int j = 0; j < 16; ++j) acc[j] += wo2[d][og * 16 + j] * hv;
  }
  float s = 0.f, ss = 0.f;
#pragma unroll
  for (int j = 0; j < 16; ++j) {
    size_t idx = ((size_t)b * CC + og * 16 + j) * TT + t0 + t;
    float o = acc[j] + res[idx];
    out[idx] = o;
    s += o; ss += o * o;
  }
  block_partial_256(s, ss, part_out + (size_t)blockIdx.x * 2);
}

// ---------------- FC (LN fused in) + relu + residual -> d_out ----------------
__global__ __launch_bounds__(256) void k_fc(const float* __restrict__ in,
                                            const float* __restrict__ lng,
                                            const float* __restrict__ lnb,
                                            const float* __restrict__ part_in,
                                            const float* __restrict__ fw,
                                            const float* __restrict__ fb,
                                            float* __restrict__ out) {
  const int TW = 32;
  int tile = blockIdx.x & 31, b = blockIdx.x >> 5;
  int t0 = tile * TW;
  __shared__ float stats[2];
  __shared__ float xs[CC][TW + 1];
  ln_stats_from_parts(part_in + (size_t)b * 32 * 2, 32, stats);
  float mu = stats[0], rs = stats[1];
  for (int i = threadIdx.x; i < CC * TW; i += 256) {
    int c = i >> 5, t = i & 31;
    float v = in[((size_t)b * CC + c) * TT + t0 + t];
    xs[c][t] = (v - mu) * rs * lng[c * TT + t0 + t] + lnb[c * TT + t0 + t];
  }
  __syncthreads();
  int t = threadIdx.x & 31, og = threadIdx.x >> 5;
  float acc[16];
#pragma unroll
  for (int j = 0; j < 16; ++j) acc[j] = fb[og * 16 + j];
  for (int c = 0; c < CC; ++c) {
    float xv = xs[c][t];
#pragma unroll
    for (int j = 0; j < 16; ++j) acc[j] += fw[(og * 16 + j) * CC + c] * xv;
  }
#pragma unroll
  for (int j = 0; j < 16; ++j) {
    size_t idx = ((size_t)b * CC + og * 16 + j) * TT + t0 + t;
    float vv = acc[j] > 0.f ? acc[j] : 0.f;
    out[idx] = vv + in[idx];
  }
}

extern "C" void kernel_launch(void* const* d_in, const int* in_sizes, int n_in,
                              void* d_out, int out_size, void* d_ws, size_t ws_size,
                              hipStream_t stream) {
  const float* x    = (const float*)d_in[0];
  const float* mask = (const float*)d_in[1];
  const float* dww  = (const float*)d_in[2];
  const float* dwb  = (const float*)d_in[3];
  const float* pww  = (const float*)d_in[4];
  const float* pwb  = (const float*)d_in[5];
  const float* n0g  = (const float*)d_in[6];
  const float* n0b  = (const float*)d_in[7];
  const float* nsg  = (const float*)d_in[8];
  const float* nsb  = (const float*)d_in[9];
  const float* neg_ = (const float*)d_in[10];
  const float* neb  = (const float*)d_in[11];
  const float* Wq   = (const float*)d_in[12];
  const float* Wk   = (const float*)d_in[13];
  const float* Wv   = (const float*)d_in[14];
  const float* Wo   = (const float*)d_in[15];
  const float* fcw  = (const float*)d_in[16];
  const float* fcb  = (const float*)d_in[17];
  float* out = (float*)d_out;

  float* W = (float*)d_ws;
  const size_t NBCT = (size_t)BB * CC * TT;
  const size_t NBTD = (size_t)BB * TT * DK;
  const size_t CT = (size_t)CC * TT;
  float* O  = W;
  float* S  = W + NBCT;
  float* HD = W + 2 * NBCT;
  float* PART0 = HD + NBTD;          // 16*128 pairs
  float* PARTS = PART0 + 4096;       // 5 stages x 16*32 pairs (1024 floats each)
  short* QB = (short*)(PARTS + 5 * 1024);
  short* KB = QB + NBTD;
  short* VT = KB + NBTD;

  k_addpos<<<BB * CC, 256, 0, stream>>>(x, O, PART0);
  // iter0: input raw, residual = LN0(input)
  k_dsconv<false, true><<<BB * 32, 256, 0, stream>>>(
      O, n0g, n0b, PART0, 128, dww, dwb, pww, pwb, S, PARTS);
  // iter1..3: input = LN_{i-1}(S_i), residual raw
  k_dsconv<true, false><<<BB * 32, 256, 0, stream>>>(
      S, nsg + 0 * CT, nsb + 0 * CT, PARTS, 32,
      dww + 1 * CC * KK, dwb + 1 * CC, pww + 1 * CT / 8 * 0 + (size_t)1 * CC * CC, pwb + 1 * CC,
      O, PARTS + 1024);
  k_dsconv<true, false><<<BB * 32, 256, 0, stream>>>(
      O, nsg + 1 * CT, nsb + 1 * CT, PARTS + 1024, 32,
      dww + 2 * CC * KK, dwb + 2 * CC, pww + (size_t)2 * CC * CC, pwb + 2 * CC,
      S, PARTS + 2048);
  k_dsconv<true, false><<<BB * 32, 256, 0, stream>>>(
      S, nsg + 2 * CT, nsb + 2 * CT, PARTS + 2048, 32,
      dww + 3 * CC * KK, dwb + 3 * CC, pww + (size_t)3 * CC * CC, pwb + 3 * CC,
      O, PARTS + 3072);
  // qkv: input = LN_3(S_4)
  k_qkv<<<BB * 32, 256, 0, stream>>>(O, nsg + 3 * CT, nsb + 3 * CT, PARTS + 3072,
                                     Wq, Wk, Wv, QB, KB, VT);
  k_attn<<<BB * 16, 256, 0, stream>>>(QB, KB, VT, mask, HD);
  // attnout: residual = S_4 raw (in O)
  k_attnout<<<BB * 32, 256, 0, stream>>>(HD, Wo, O, S, PARTS + 4096);
  // fc: input = LN_e(S_5), residual = S_5 raw
  k_fc<<<BB * 32, 256, 0, stream>>>(S, neg_, neb, PARTS + 4096, fcw, fcb, out);
}

// Round 3
// 232.571 us; speedup vs baseline: 3.1607x; 2.3873x over previous
//
#include <hip/hip_runtime.h>
#include <math.h>

#define BB 16
#define CC 128
#define TT 1024
#define KK 7
#define DK 64

typedef float f32x4 __attribute__((ext_vector_type(4)));
typedef short s16x8 __attribute__((ext_vector_type(8)));

__device__ inline short f2bf(float f) {
  union { float f; unsigned u; } v; v.f = f;
  unsigned r = (v.u + 0x7FFFu + ((v.u >> 16) & 1u)) >> 16;
  return (short)r;
}

// block-wide (256 threads) reduce of (s,ss) -> dst[0..1]
__device__ inline void block_partial_256(float s, float ss, float* dst) {
#pragma unroll
  for (int off = 32; off; off >>= 1) { s += __shfl_xor(s, off); ss += __shfl_xor(ss, off); }
  __shared__ float red[8];
  int w = threadIdx.x >> 6;
  if ((threadIdx.x & 63) == 0) { red[2 * w] = s; red[2 * w + 1] = ss; }
  __syncthreads();
  if (threadIdx.x == 0) {
    for (int i = 1; i < 4; ++i) { s += red[2 * i]; ss += red[2 * i + 1]; }
    dst[0] = s; dst[1] = ss;
  }
}

// reduce n partial (sum,sumsq) pairs for one batch -> sh[0]=mu, sh[1]=rsqrt(var+eps)
__device__ inline void ln_stats_from_parts(const float* part_batch, int n, float* sh) {
  if (threadIdx.x < 64) {
    float s = 0.f, ss = 0.f;
    for (int i = threadIdx.x; i < n; i += 64) { s += part_batch[2 * i]; ss += part_batch[2 * i + 1]; }
#pragma unroll
    for (int off = 32; off; off >>= 1) { s += __shfl_xor(s, off); ss += __shfl_xor(ss, off); }
    if (threadIdx.x == 0) {
      const float invN = 1.f / (float)(CC * TT);
      float mu = s * invN;
      sh[0] = mu;
      sh[1] = rsqrtf(ss * invN - mu * mu + 1e-5f);
    }
  }
  __syncthreads();
}

// ---------------- one-time weight prep: bf16 convert (+ transpose/fold) ----------------
__global__ __launch_bounds__(256) void k_prep(const float* __restrict__ pww,
                                              const float* __restrict__ Wq,
                                              const float* __restrict__ Wk,
                                              const float* __restrict__ Wv,
                                              const float* __restrict__ Wo,
                                              const float* __restrict__ fcw,
                                              short* __restrict__ pwwb,
                                              short* __restrict__ wqkvb,
                                              short* __restrict__ wo2b,
                                              short* __restrict__ fcwb) {
  int i = blockIdx.x * 256 + threadIdx.x;  // total 114688
  if (i < 65536) { pwwb[i] = f2bf(pww[i]); return; }
  i -= 65536;
  if (i < 24576) {  // wqkvb[m][c] = W{q,k,v}[c][m&63]
    int m = i >> 7, c = i & 127;
    int sel = m >> 6, d = m & 63;
    const float* srcp = sel == 0 ? Wq : (sel == 1 ? Wk : Wv);
    wqkvb[i] = f2bf(srcp[c * DK + d]);
    return;
  }
  i -= 24576;
  if (i < 8192) {  // wo2b[o][d] = Wo[d][o] + Wo[d+64][o]
    int o = i >> 6, d = i & 63;
    wo2b[i] = f2bf(Wo[d * CC + o] + Wo[(d + 64) * CC + o]);
    return;
  }
  i -= 8192;
  fcwb[i] = f2bf(fcw[i]);
}

// ---------------- pos encoding + add (+ LN partials) ----------------
__global__ __launch_bounds__(256) void k_addpos(const float* __restrict__ x,
                                                float* __restrict__ out,
                                                float* __restrict__ part) {
  int bc = blockIdx.x;  // b*CC + c
  int c = bc & (CC - 1);
  float ce = (float)(c & ~1);
  float freq = expf(-(ce / (float)CC) * 9.210340371976184f);
  float phase = (c & 1) ? 1.5707963267948966f : 0.0f;
  const float* xr = x + (size_t)bc * TT;
  float* orow = out + (size_t)bc * TT;
  float s = 0.f, ss = 0.f;
  for (int t = threadIdx.x; t < TT; t += 256) {
    float v = xr[t] + sinf((float)t * freq + phase);
    orow[t] = v;
    s += v; ss += v * v;
  }
  block_partial_256(s, ss, part + (size_t)bc * 2);
}

// ------- dsconv: [LN-in] depthwise(fp32) -> MFMA pointwise + relu + [LN-res] residual -------
template <bool LN_IN, bool LN_RES>
__global__ __launch_bounds__(256) void k_dsconv(const float* __restrict__ in,
                                                const float* __restrict__ lng,
                                                const float* __restrict__ lnb,
                                                const float* __restrict__ part_in, int npart,
                                                const float* __restrict__ dww,
                                                const float* __restrict__ dwb,
                                                const short* __restrict__ pwwb,
                                                const float* __restrict__ pwb,
                                                float* __restrict__ out,
                                                float* __restrict__ part_out) {
  int tile = blockIdx.x & 31, b = blockIdx.x >> 5;
  int t0 = tile * 32;
  __shared__ float stats[2];
  __shared__ float xs[CC][39];                // 38 used (32+6 halo), odd stride
  __shared__ __align__(16) short Dt[32][136]; // depthwise out, transposed [t][c]
  ln_stats_from_parts(part_in + (size_t)b * npart * 2, npart, stats);
  float mu = stats[0], rs = stats[1];

  for (int i = threadIdx.x; i < CC * 38; i += 256) {
    int c = i / 38, j = i - c * 38;
    int t = t0 + j - 3;
    float v = 0.f;
    if (t >= 0 && t < TT) {
      v = in[((size_t)b * CC + c) * TT + t];
      if (LN_IN) v = (v - mu) * rs * lng[c * TT + t] + lnb[c * TT + t];
    }
    xs[c][j] = v;
  }
  __syncthreads();
  for (int i = threadIdx.x; i < 32 * CC; i += 256) {
    int t = i >> 7, c = i & 127;  // lanes: consecutive c -> conflict-free Dt write
    float a = dwb[c];
#pragma unroll
    for (int j = 0; j < KK; ++j) a += dww[c * KK + j] * xs[c][t + j];
    Dt[t][c] = f2bf(a);
  }
  __syncthreads();

  int w = threadIdx.x >> 6, lane = threadIdx.x & 63;
  int lo = lane & 15, hi = lane >> 4;
  f32x4 acc[2][2];
#pragma unroll
  for (int mt = 0; mt < 2; ++mt)
#pragma unroll
    for (int nt = 0; nt < 2; ++nt) { acc[mt][nt][0] = 0.f; acc[mt][nt][1] = 0.f; acc[mt][nt][2] = 0.f; acc[mt][nt][3] = 0.f; }
#pragma unroll
  for (int ks = 0; ks < 4; ++ks) {
    s16x8 b0 = *(const s16x8*)&Dt[lo][ks * 32 + hi * 8];
    s16x8 b1 = *(const s16x8*)&Dt[16 + lo][ks * 32 + hi * 8];
    s16x8 a0 = *(const s16x8*)&pwwb[(size_t)(w * 32 + lo) * CC + ks * 32 + hi * 8];
    s16x8 a1 = *(const s16x8*)&pwwb[(size_t)(w * 32 + 16 + lo) * CC + ks * 32 + hi * 8];
    acc[0][0] = __builtin_amdgcn_mfma_f32_16x16x32_bf16(a0, b0, acc[0][0], 0, 0, 0);
    acc[0][1] = __builtin_amdgcn_mfma_f32_16x16x32_bf16(a0, b1, acc[0][1], 0, 0, 0);
    acc[1][0] = __builtin_amdgcn_mfma_f32_16x16x32_bf16(a1, b0, acc[1][0], 0, 0, 0);
    acc[1][1] = __builtin_amdgcn_mfma_f32_16x16x32_bf16(a1, b1, acc[1][1], 0, 0, 0);
  }

  float s = 0.f, ss = 0.f;
#pragma unroll
  for (int mt = 0; mt < 2; ++mt)
#pragma unroll
    for (int nt = 0; nt < 2; ++nt)
#pragma unroll
      for (int r = 0; r < 4; ++r) {
        int row = w * 32 + mt * 16 + hi * 4 + r;
        int t = t0 + nt * 16 + lo;
        float v = acc[mt][nt][r] + pwb[row];
        v = v > 0.f ? v : 0.f;
        size_t idx = ((size_t)b * CC + row) * TT + t;
        float rv = in[idx];
        if (LN_RES) rv = (rv - mu) * rs * lng[row * TT + t] + lnb[row * TT + t];
        v += rv;
        out[idx] = v;
        s += v; ss += v * v;
      }
  block_partial_256(s, ss, part_out + (size_t)blockIdx.x * 2);
}

// ---------------- q,k,v projections: MFMA, M=192 stacked ----------------
__global__ __launch_bounds__(256) void k_qkv(const float* __restrict__ in,
                                             const float* __restrict__ lng,
                                             const float* __restrict__ lnb,
                                             const float* __restrict__ part_in,
                                             const short* __restrict__ wqkvb,
                                             short* __restrict__ q,
                                             short* __restrict__ k,
                                             short* __restrict__ vt) {
  int tile = blockIdx.x & 31, b = blockIdx.x >> 5;
  int t0 = tile * 32;
  __shared__ float stats[2];
  __shared__ __align__(16) short Dt[32][136];
  ln_stats_from_parts(part_in + (size_t)b * 64, 32, stats);
  float mu = stats[0], rs = stats[1];
  for (int i = threadIdx.x; i < CC * 32; i += 256) {
    int c = i >> 5, t = i & 31;  // coalesced global read over t
    float v = in[((size_t)b * CC + c) * TT + t0 + t];
    Dt[t][c] = f2bf((v - mu) * rs * lng[c * TT + t0 + t] + lnb[c * TT + t0 + t]);
  }
  __syncthreads();

  int w = threadIdx.x >> 6, lane = threadIdx.x & 63;
  int lo = lane & 15, hi = lane >> 4;
  f32x4 acc[3][2];
#pragma unroll
  for (int mt = 0; mt < 3; ++mt)
#pragma unroll
    for (int nt = 0; nt < 2; ++nt) { acc[mt][nt][0] = 0.f; acc[mt][nt][1] = 0.f; acc[mt][nt][2] = 0.f; acc[mt][nt][3] = 0.f; }
#pragma unroll
  for (int ks = 0; ks < 4; ++ks) {
    s16x8 b0 = *(const s16x8*)&Dt[lo][ks * 32 + hi * 8];
    s16x8 b1 = *(const s16x8*)&Dt[16 + lo][ks * 32 + hi * 8];
#pragma unroll
    for (int mt = 0; mt < 3; ++mt) {
      s16x8 a = *(const s16x8*)&wqkvb[(size_t)(w * 48 + mt * 16 + lo) * CC + ks * 32 + hi * 8];
      acc[mt][0] = __builtin_amdgcn_mfma_f32_16x16x32_bf16(a, b0, acc[mt][0], 0, 0, 0);
      acc[mt][1] = __builtin_amdgcn_mfma_f32_16x16x32_bf16(a, b1, acc[mt][1], 0, 0, 0);
    }
  }
#pragma unroll
  for (int mt = 0; mt < 3; ++mt)
#pragma unroll
    for (int nt = 0; nt < 2; ++nt) {
      int m0 = w * 48 + mt * 16 + hi * 4;
      int t = t0 + nt * 16 + lo;
      short4 pk;
      pk.x = f2bf(acc[mt][nt][0]); pk.y = f2bf(acc[mt][nt][1]);
      pk.z = f2bf(acc[mt][nt][2]); pk.w = f2bf(acc[mt][nt][3]);
      if (m0 < 64) {
        *(short4*)(q + ((size_t)b * TT + t) * DK + m0) = pk;
      } else if (m0 < 128) {
        *(short4*)(k + ((size_t)b * TT + t) * DK + (m0 - 64)) = pk;
      } else {
        int d = m0 - 128;
        vt[((size_t)b * DK + d) * TT + t] = pk.x;
        vt[((size_t)b * DK + d + 1) * TT + t] = pk.y;
        vt[((size_t)b * DK + d + 2) * TT + t] = pk.z;
        vt[((size_t)b * DK + d + 3) * TT + t] = pk.w;
      }
    }
}

// ---------------- flash attention, bf16 MFMA, 32 Q-rows / 128 threads ----------------
__global__ __launch_bounds__(128) void k_attn(const short* __restrict__ qb,
                                              const short* __restrict__ kbuf,
                                              const short* __restrict__ vtb,
                                              const float* __restrict__ mask,
                                              short* __restrict__ head) {
  int b = blockIdx.x >> 5, qt = blockIdx.x & 31;
  int w = threadIdx.x >> 6, lane = threadIdx.x & 63;
  int lo = lane & 15, hi = lane >> 4;

  __shared__ __align__(16) short ks[64][72];
  __shared__ __align__(16) short vt[64][72];
  __shared__ __align__(16) short ps[2][16][72];
  __shared__ float ms[64];

  const short* qp = qb + ((size_t)b * TT + qt * 32 + w * 16 + lo) * DK + hi * 8;
  s16x8 aq0 = *(const s16x8*)qp;
  s16x8 aq1 = *(const s16x8*)(qp + 32);

  f32x4 acc[4];
  float m_i[4], l_i[4];
#pragma unroll
  for (int r = 0; r < 4; ++r) {
    m_i[r] = -3.0e38f; l_i[r] = 0.f;
#pragma unroll
    for (int nt = 0; nt < 4; ++nt) acc[nt][r] = 0.f;
  }
  const float scale = 0.125f;

  for (int kb2 = 0; kb2 < TT / 64; ++kb2) {
    __syncthreads();
    for (int i = threadIdx.x; i < 512; i += 128) {
      int r = i >> 3, ch = i & 7;
      *(s16x8*)&ks[r][ch * 8] =
          *(const s16x8*)(kbuf + ((size_t)b * TT + kb2 * 64 + r) * DK + ch * 8);
      *(s16x8*)&vt[r][ch * 8] =
          *(const s16x8*)(vtb + ((size_t)b * DK + r) * TT + kb2 * 64 + ch * 8);
    }
    if (threadIdx.x < 64) ms[threadIdx.x] = mask[(size_t)b * TT + kb2 * 64 + threadIdx.x];
    __syncthreads();

    f32x4 sc[4];
#pragma unroll
    for (int nt = 0; nt < 4; ++nt) {
      f32x4 z; z[0] = 0.f; z[1] = 0.f; z[2] = 0.f; z[3] = 0.f;
      s16x8 bk0 = *(const s16x8*)&ks[nt * 16 + lo][hi * 8];
      s16x8 bk1 = *(const s16x8*)&ks[nt * 16 + lo][32 + hi * 8];
      z = __builtin_amdgcn_mfma_f32_16x16x32_bf16(aq0, bk0, z, 0, 0, 0);
      z = __builtin_amdgcn_mfma_f32_16x16x32_bf16(aq1, bk1, z, 0, 0, 0);
      sc[nt] = z;
    }
#pragma unroll
    for (int nt = 0; nt < 4; ++nt) {
      float mv = ms[nt * 16 + lo];
      float addv = (1.f - mv) * -1e30f;
#pragma unroll
      for (int r = 0; r < 4; ++r) sc[nt][r] = sc[nt][r] * scale * mv + addv;
    }
    float alpha[4];
#pragma unroll
    for (int r = 0; r < 4; ++r) {
      float m0 = fmaxf(fmaxf(sc[0][r], sc[1][r]), fmaxf(sc[2][r], sc[3][r]));
#pragma unroll
      for (int off = 1; off < 16; off <<= 1) m0 = fmaxf(m0, __shfl_xor(m0, off));
      float mn = fmaxf(m_i[r], m0);
      alpha[r] = __expf(m_i[r] - mn);
      m_i[r] = mn;
    }
    float psum[4] = {0.f, 0.f, 0.f, 0.f};
#pragma unroll
    for (int nt = 0; nt < 4; ++nt)
#pragma unroll
      for (int r = 0; r < 4; ++r) {
        float p = __expf(sc[nt][r] - m_i[r]);
        psum[r] += p;
        ps[w][hi * 4 + r][nt * 16 + lo] = f2bf(p);
      }
#pragma unroll
    for (int r = 0; r < 4; ++r) {
      float sum = psum[r];
#pragma unroll
      for (int off = 1; off < 16; off <<= 1) sum += __shfl_xor(sum, off);
      l_i[r] = l_i[r] * alpha[r] + sum;
    }
#pragma unroll
    for (int nt = 0; nt < 4; ++nt)
#pragma unroll
      for (int r = 0; r < 4; ++r) acc[nt][r] *= alpha[r];

    s16x8 ap0 = *(const s16x8*)&ps[w][lo][hi * 8];
    s16x8 ap1 = *(const s16x8*)&ps[w][lo][32 + hi * 8];
#pragma unroll
    for (int nt = 0; nt < 4; ++nt) {
      s16x8 bv0 = *(const s16x8*)&vt[nt * 16 + lo][hi * 8];
      s16x8 bv1 = *(const s16x8*)&vt[nt * 16 + lo][32 + hi * 8];
      acc[nt] = __builtin_amdgcn_mfma_f32_16x16x32_bf16(ap0, bv0, acc[nt], 0, 0, 0);
      acc[nt] = __builtin_amdgcn_mfma_f32_16x16x32_bf16(ap1, bv1, acc[nt], 0, 0, 0);
    }
  }
#pragma unroll
  for (int r = 0; r < 4; ++r) {
    int row = qt * 32 + w * 16 + hi * 4 + r;
    float qm = mask[(size_t)b * TT + row];
    float inv = qm / l_i[r];
#pragma unroll
    for (int nt = 0; nt < 4; ++nt)
      head[((size_t)b * TT + row) * DK + nt * 16 + lo] = f2bf(acc[nt][r] * inv);
  }
}

// ---------------- heads@Wo2 (MFMA, K=64) + residual (+ partials) ----------------
__global__ __launch_bounds__(256) void k_attnout(const short* __restrict__ head,
                                                 const short* __restrict__ wo2b,
                                                 const float* __restrict__ res,
                                                 float* __restrict__ out,
                                                 float* __restrict__ part_out) {
  int tile = blockIdx.x & 31, b = blockIdx.x >> 5;
  int t0 = tile * 32;
  __shared__ __align__(16) short Ht[32][72];
  {
    int i = threadIdx.x;  // 256 = 32 rows x 8 chunks
    int t = i >> 3, ch = i & 7;
    *(s16x8*)&Ht[t][ch * 8] =
        *(const s16x8*)(head + ((size_t)b * TT + t0 + t) * DK + ch * 8);
  }
  __syncthreads();

  int w = threadIdx.x >> 6, lane = threadIdx.x & 63;
  int lo = lane & 15, hi = lane >> 4;
  f32x4 acc[2][2];
#pragma unroll
  for (int mt = 0; mt < 2; ++mt)
#pragma unroll
    for (int nt = 0; nt < 2; ++nt) { acc[mt][nt][0] = 0.f; acc[mt][nt][1] = 0.f; acc[mt][nt][2] = 0.f; acc[mt][nt][3] = 0.f; }
#pragma unroll
  for (int ks = 0; ks < 2; ++ks) {
    s16x8 b0 = *(const s16x8*)&Ht[lo][ks * 32 + hi * 8];
    s16x8 b1 = *(const s16x8*)&Ht[16 + lo][ks * 32 + hi * 8];
    s16x8 a0 = *(const s16x8*)&wo2b[(size_t)(w * 32 + lo) * DK + ks * 32 + hi * 8];
    s16x8 a1 = *(const s16x8*)&wo2b[(size_t)(w * 32 + 16 + lo) * DK + ks * 32 + hi * 8];
    acc[0][0] = __builtin_amdgcn_mfma_f32_16x16x32_bf16(a0, b0, acc[0][0], 0, 0, 0);
    acc[0][1] = __builtin_amdgcn_mfma_f32_16x16x32_bf16(a0, b1, acc[0][1], 0, 0, 0);
    acc[1][0] = __builtin_amdgcn_mfma_f32_16x16x32_bf16(a1, b0, acc[1][0], 0, 0, 0);
    acc[1][1] = __builtin_amdgcn_mfma_f32_16x16x32_bf16(a1, b1, acc[1][1], 0, 0, 0);
  }
  float s = 0.f, ss = 0.f;
#pragma unroll
  for (int mt = 0; mt < 2; ++mt)
#pragma unroll
    for (int nt = 0; nt < 2; ++nt)
#pragma unroll
      for (int r = 0; r < 4; ++r) {
        int row = w * 32 + mt * 16 + hi * 4 + r;
        int t = t0 + nt * 16 + lo;
        size_t idx = ((size_t)b * CC + row) * TT + t;
        float v = acc[mt][nt][r] + res[idx];
        out[idx] = v;
        s += v; ss += v * v;
      }
  block_partial_256(s, ss, part_out + (size_t)blockIdx.x * 2);
}

// ---------------- FC (LN fused in, MFMA) + relu + residual -> d_out ----------------
__global__ __launch_bounds__(256) void k_fc(const float* __restrict__ in,
                                            const float* __restrict__ lng,
                                            const float* __restrict__ lnb,
                                            const float* __restrict__ part_in,
                                            const short* __restrict__ fcwb,
                                            const float* __restrict__ fb,
                                            float* __restrict__ out) {
  int tile = blockIdx.x & 31, b = blockIdx.x >> 5;
  int t0 = tile * 32;
  __shared__ float stats[2];
  __shared__ __align__(16) short Dt[32][136];
  ln_stats_from_parts(part_in + (size_t)b * 64, 32, stats);
  float mu = stats[0], rs = stats[1];
  for (int i = threadIdx.x; i < CC * 32; i += 256) {
    int c = i >> 5, t = i & 31;
    float v = in[((size_t)b * CC + c) * TT + t0 + t];
    Dt[t][c] = f2bf((v - mu) * rs * lng[c * TT + t0 + t] + lnb[c * TT + t0 + t]);
  }
  __syncthreads();

  int w = threadIdx.x >> 6, lane = threadIdx.x & 63;
  int lo = lane & 15, hi = lane >> 4;
  f32x4 acc[2][2];
#pragma unroll
  for (int mt = 0; mt < 2; ++mt)
#pragma unroll
    for (int nt = 0; nt < 2; ++nt) { acc[mt][nt][0] = 0.f; acc[mt][nt][1] = 0.f; acc[mt][nt][2] = 0.f; acc[mt][nt][3] = 0.f; }
#pragma unroll
  for (int ks = 0; ks < 4; ++ks) {
    s16x8 b0 = *(const s16x8*)&Dt[lo][ks * 32 + hi * 8];
    s16x8 b1 = *(const s16x8*)&Dt[16 + lo][ks * 32 + hi * 8];
    s16x8 a0 = *(const s16x8*)&fcwb[(size_t)(w * 32 + lo) * CC + ks * 32 + hi * 8];
    s16x8 a1 = *(const s16x8*)&fcwb[(size_t)(w * 32 + 16 + lo) * CC + ks * 32 + hi * 8];
    acc[0][0] = __builtin_amdgcn_mfma_f32_16x16x32_bf16(a0, b0, acc[0][0], 0, 0, 0);
    acc[0][1] = __builtin_amdgcn_mfma_f32_16x16x32_bf16(a0, b1, acc[0][1], 0, 0, 0);
    acc[1][0] = __builtin_amdgcn_mfma_f32_16x16x32_bf16(a1, b0, acc[1][0], 0, 0, 0);
    acc[1][1] = __builtin_amdgcn_mfma_f32_16x16x32_bf16(a1, b1, acc[1][1], 0, 0, 0);
  }
#pragma unroll
  for (int mt = 0; mt < 2; ++mt)
#pragma unroll
    for (int nt = 0; nt < 2; ++nt)
#pragma unroll
      for (int r = 0; r < 4; ++r) {
        int row = w * 32 + mt * 16 + hi * 4 + r;
        int t = t0 + nt * 16 + lo;
        size_t idx = ((size_t)b * CC + row) * TT + t;
        float v = acc[mt][nt][r] + fb[row];
        v = v > 0.f ? v : 0.f;
        out[idx] = v + in[idx];
      }
}

extern "C" void kernel_launch(void* const* d_in, const int* in_sizes, int n_in,
                              void* d_out, int out_size, void* d_ws, size_t ws_size,
                              hipStream_t stream) {
  const float* x    = (const float*)d_in[0];
  const float* mask = (const float*)d_in[1];
  const float* dww  = (const float*)d_in[2];
  const float* dwb  = (const float*)d_in[3];
  const float* pww  = (const float*)d_in[4];
  const float* pwb  = (const float*)d_in[5];
  const float* n0g  = (const float*)d_in[6];
  const float* n0b  = (const float*)d_in[7];
  const float* nsg  = (const float*)d_in[8];
  const float* nsb  = (const float*)d_in[9];
  const float* neg_ = (const float*)d_in[10];
  const float* neb  = (const float*)d_in[11];
  const float* Wq   = (const float*)d_in[12];
  const float* Wk   = (const float*)d_in[13];
  const float* Wv   = (const float*)d_in[14];
  const float* Wo   = (const float*)d_in[15];
  const float* fcw  = (const float*)d_in[16];
  const float* fcb  = (const float*)d_in[17];
  float* out = (float*)d_out;

  float* W = (float*)d_ws;
  const size_t NBCT = (size_t)BB * CC * TT;
  const size_t NBTD = (size_t)BB * TT * DK;
  const size_t CT = (size_t)CC * TT;
  float* O     = W;
  float* S     = W + NBCT;
  float* PART0 = W + 2 * NBCT;       // 16*128 pairs
  float* PARTS = PART0 + 4096;       // 5 stages x 16*32 pairs
  short* QB    = (short*)(PARTS + 5 * 1024);
  short* KB    = QB + NBTD;
  short* VT    = KB + NBTD;
  short* HDB   = VT + NBTD;
  short* PWWB  = HDB + NBTD;         // 4*128*128
  short* WQKVB = PWWB + 65536;       // 192*128
  short* WO2B  = WQKVB + 24576;      // 128*64
  short* FCWB  = WO2B + 8192;        // 128*128

  k_prep<<<448, 256, 0, stream>>>(pww, Wq, Wk, Wv, Wo, fcw, PWWB, WQKVB, WO2B, FCWB);
  k_addpos<<<BB * CC, 256, 0, stream>>>(x, O, PART0);
  // iter0: input raw, residual = LN0(input)
  k_dsconv<false, true><<<BB * 32, 256, 0, stream>>>(
      O, n0g, n0b, PART0, 128, dww, dwb, PWWB, pwb, S, PARTS);
  k_dsconv<true, false><<<BB * 32, 256, 0, stream>>>(
      S, nsg + 0 * CT, nsb + 0 * CT, PARTS, 32,
      dww + 1 * CC * KK, dwb + 1 * CC, PWWB + 1 * CC * CC, pwb + 1 * CC, O, PARTS + 1024);
  k_dsconv<true, false><<<BB * 32, 256, 0, stream>>>(
      O, nsg + 1 * CT, nsb + 1 * CT, PARTS + 1024, 32,
      dww + 2 * CC * KK, dwb + 2 * CC, PWWB + 2 * CC * CC, pwb + 2 * CC, S, PARTS + 2048);
  k_dsconv<true, false><<<BB * 32, 256, 0, stream>>>(
      S, nsg + 2 * CT, nsb + 2 * CT, PARTS + 2048, 32,
      dww + 3 * CC * KK, dwb + 3 * CC, PWWB + 3 * CC * CC, pwb + 3 * CC, O, PARTS + 3072);
  // qkv: input = LN_3(O)
  k_qkv<<<BB * 32, 256, 0, stream>>>(O, nsg + 3 * CT, nsb + 3 * CT, PARTS + 3072,
                                     WQKVB, QB, KB, VT);
  k_attn<<<BB * 32, 128, 0, stream>>>(QB, KB, VT, mask, HDB);
  // attnout: residual = O raw
  k_attnout<<<BB * 32, 256, 0, stream>>>(HDB, WO2B, O, S, PARTS + 4096);
  // fc: input = LN_e(S), residual = S raw
  k_fc<<<BB * 32, 256, 0, stream>>>(S, neg_, neb, PARTS + 4096, FCWB, fcb, out);
}

// Round 4
// 218.592 us; speedup vs baseline: 3.3629x; 1.0639x over previous
//
#include <hip/hip_runtime.h>
#include <math.h>

#define BB 16
#define CC 128
#define TT 1024
#define KK 7
#define DK 64
#define NSPLIT 4

typedef float f32x4 __attribute__((ext_vector_type(4)));
typedef short s16x8 __attribute__((ext_vector_type(8)));

__device__ inline short f2bf(float f) {
  union { float f; unsigned u; } v; v.f = f;
  unsigned r = (v.u + 0x7FFFu + ((v.u >> 16) & 1u)) >> 16;
  return (short)r;
}

// block-wide (256 threads) reduce of (s,ss) -> dst[0..1]
__device__ inline void block_partial_256(float s, float ss, float* dst) {
#pragma unroll
  for (int off = 32; off; off >>= 1) { s += __shfl_xor(s, off); ss += __shfl_xor(ss, off); }
  __shared__ float red[8];
  int w = threadIdx.x >> 6;
  if ((threadIdx.x & 63) == 0) { red[2 * w] = s; red[2 * w + 1] = ss; }
  __syncthreads();
  if (threadIdx.x == 0) {
    for (int i = 1; i < 4; ++i) { s += red[2 * i]; ss += red[2 * i + 1]; }
    dst[0] = s; dst[1] = ss;
  }
}

// reduce n partial (sum,sumsq) pairs for one batch -> sh[0]=mu, sh[1]=rsqrt(var+eps)
__device__ inline void ln_stats_from_parts(const float* part_batch, int n, float* sh) {
  if (threadIdx.x < 64) {
    float s = 0.f, ss = 0.f;
    for (int i = threadIdx.x; i < n; i += 64) { s += part_batch[2 * i]; ss += part_batch[2 * i + 1]; }
#pragma unroll
    for (int off = 32; off; off >>= 1) { s += __shfl_xor(s, off); ss += __shfl_xor(ss, off); }
    if (threadIdx.x == 0) {
      const float invN = 1.f / (float)(CC * TT);
      float mu = s * invN;
      sh[0] = mu;
      sh[1] = rsqrtf(ss * invN - mu * mu + 1e-5f);
    }
  }
  __syncthreads();
}

// ---------------- one-time weight prep: bf16 convert (+ transpose/fold) ----------------
__global__ __launch_bounds__(256) void k_prep(const float* __restrict__ pww,
                                              const float* __restrict__ Wq,
                                              const float* __restrict__ Wk,
                                              const float* __restrict__ Wv,
                                              const float* __restrict__ Wo,
                                              const float* __restrict__ fcw,
                                              short* __restrict__ pwwb,
                                              short* __restrict__ wqkvb,
                                              short* __restrict__ wo2b,
                                              short* __restrict__ fcwb) {
  int i = blockIdx.x * 256 + threadIdx.x;  // total 114688
  if (i < 65536) { pwwb[i] = f2bf(pww[i]); return; }
  i -= 65536;
  if (i < 24576) {  // wqkvb[m][c] = W{q,k,v}[c][m&63]
    int m = i >> 7, c = i & 127;
    int sel = m >> 6, d = m & 63;
    const float* srcp = sel == 0 ? Wq : (sel == 1 ? Wk : Wv);
    wqkvb[i] = f2bf(srcp[c * DK + d]);
    return;
  }
  i -= 24576;
  if (i < 8192) {  // wo2b[o][d] = Wo[d][o] + Wo[d+64][o]
    int o = i >> 6, d = i & 63;
    wo2b[i] = f2bf(Wo[d * CC + o] + Wo[(d + 64) * CC + o]);
    return;
  }
  i -= 8192;
  fcwb[i] = f2bf(fcw[i]);
}

// ---------------- pos encoding + add (+ LN partials) ----------------
__global__ __launch_bounds__(256) void k_addpos(const float* __restrict__ x,
                                                float* __restrict__ out,
                                                float* __restrict__ part) {
  int bc = blockIdx.x;  // b*CC + c
  int c = bc & (CC - 1);
  float ce = (float)(c & ~1);
  float freq = expf(-(ce / (float)CC) * 9.210340371976184f);
  float phase = (c & 1) ? 1.5707963267948966f : 0.0f;
  const float* xr = x + (size_t)bc * TT;
  float* orow = out + (size_t)bc * TT;
  float s = 0.f, ss = 0.f;
  for (int t = threadIdx.x; t < TT; t += 256) {
    float v = xr[t] + sinf((float)t * freq + phase);
    orow[t] = v;
    s += v; ss += v * v;
  }
  block_partial_256(s, ss, part + (size_t)bc * 2);
}

// ------- dsconv: [LN-in] depthwise(fp32) -> MFMA pointwise + relu + [LN-res] residual -------
template <bool LN_IN, bool LN_RES>
__global__ __launch_bounds__(256) void k_dsconv(const float* __restrict__ in,
                                                const float* __restrict__ lng,
                                                const float* __restrict__ lnb,
                                                const float* __restrict__ part_in, int npart,
                                                const float* __restrict__ dww,
                                                const float* __restrict__ dwb,
                                                const short* __restrict__ pwwb,
                                                const float* __restrict__ pwb,
                                                float* __restrict__ out,
                                                float* __restrict__ part_out) {
  int tile = blockIdx.x & 31, b = blockIdx.x >> 5;
  int t0 = tile * 32;
  __shared__ float stats[2];
  __shared__ float xs[CC][39];                // 38 used (32+6 halo), odd stride
  __shared__ __align__(16) short Dt[32][136]; // depthwise out, transposed [t][c]
  ln_stats_from_parts(part_in + (size_t)b * npart * 2, npart, stats);
  float mu = stats[0], rs = stats[1];

  for (int i = threadIdx.x; i < CC * 38; i += 256) {
    int c = i / 38, j = i - c * 38;
    int t = t0 + j - 3;
    float v = 0.f;
    if (t >= 0 && t < TT) {
      v = in[((size_t)b * CC + c) * TT + t];
      if (LN_IN) v = (v - mu) * rs * lng[c * TT + t] + lnb[c * TT + t];
    }
    xs[c][j] = v;
  }
  __syncthreads();
  for (int i = threadIdx.x; i < 32 * CC; i += 256) {
    int t = i >> 7, c = i & 127;  // lanes: consecutive c -> conflict-free Dt write
    float a = dwb[c];
#pragma unroll
    for (int j = 0; j < KK; ++j) a += dww[c * KK + j] * xs[c][t + j];
    Dt[t][c] = f2bf(a);
  }
  __syncthreads();

  int w = threadIdx.x >> 6, lane = threadIdx.x & 63;
  int lo = lane & 15, hi = lane >> 4;
  f32x4 acc[2][2];
#pragma unroll
  for (int mt = 0; mt < 2; ++mt)
#pragma unroll
    for (int nt = 0; nt < 2; ++nt) { acc[mt][nt][0] = 0.f; acc[mt][nt][1] = 0.f; acc[mt][nt][2] = 0.f; acc[mt][nt][3] = 0.f; }
#pragma unroll
  for (int ks = 0; ks < 4; ++ks) {
    s16x8 b0 = *(const s16x8*)&Dt[lo][ks * 32 + hi * 8];
    s16x8 b1 = *(const s16x8*)&Dt[16 + lo][ks * 32 + hi * 8];
    s16x8 a0 = *(const s16x8*)&pwwb[(size_t)(w * 32 + lo) * CC + ks * 32 + hi * 8];
    s16x8 a1 = *(const s16x8*)&pwwb[(size_t)(w * 32 + 16 + lo) * CC + ks * 32 + hi * 8];
    acc[0][0] = __builtin_amdgcn_mfma_f32_16x16x32_bf16(a0, b0, acc[0][0], 0, 0, 0);
    acc[0][1] = __builtin_amdgcn_mfma_f32_16x16x32_bf16(a0, b1, acc[0][1], 0, 0, 0);
    acc[1][0] = __builtin_amdgcn_mfma_f32_16x16x32_bf16(a1, b0, acc[1][0], 0, 0, 0);
    acc[1][1] = __builtin_amdgcn_mfma_f32_16x16x32_bf16(a1, b1, acc[1][1], 0, 0, 0);
  }

  float s = 0.f, ss = 0.f;
#pragma unroll
  for (int mt = 0; mt < 2; ++mt)
#pragma unroll
    for (int nt = 0; nt < 2; ++nt)
#pragma unroll
      for (int r = 0; r < 4; ++r) {
        int row = w * 32 + mt * 16 + hi * 4 + r;
        int t = t0 + nt * 16 + lo;
        float v = acc[mt][nt][r] + pwb[row];
        v = v > 0.f ? v : 0.f;
        size_t idx = ((size_t)b * CC + row) * TT + t;
        float rv = in[idx];
        if (LN_RES) rv = (rv - mu) * rs * lng[row * TT + t] + lnb[row * TT + t];
        v += rv;
        out[idx] = v;
        s += v; ss += v * v;
      }
  block_partial_256(s, ss, part_out + (size_t)blockIdx.x * 2);
}

// ---------------- q,k,v projections: MFMA, M=192 stacked ----------------
__global__ __launch_bounds__(256) void k_qkv(const float* __restrict__ in,
                                             const float* __restrict__ lng,
                                             const float* __restrict__ lnb,
                                             const float* __restrict__ part_in,
                                             const short* __restrict__ wqkvb,
                                             short* __restrict__ q,
                                             short* __restrict__ k,
                                             short* __restrict__ vt) {
  int tile = blockIdx.x & 31, b = blockIdx.x >> 5;
  int t0 = tile * 32;
  __shared__ float stats[2];
  __shared__ __align__(16) short Dt[32][136];
  ln_stats_from_parts(part_in + (size_t)b * 64, 32, stats);
  float mu = stats[0], rs = stats[1];
  for (int i = threadIdx.x; i < CC * 32; i += 256) {
    int c = i >> 5, t = i & 31;  // coalesced global read over t
    float v = in[((size_t)b * CC + c) * TT + t0 + t];
    Dt[t][c] = f2bf((v - mu) * rs * lng[c * TT + t0 + t] + lnb[c * TT + t0 + t]);
  }
  __syncthreads();

  int w = threadIdx.x >> 6, lane = threadIdx.x & 63;
  int lo = lane & 15, hi = lane >> 4;
  f32x4 acc[3][2];
#pragma unroll
  for (int mt = 0; mt < 3; ++mt)
#pragma unroll
    for (int nt = 0; nt < 2; ++nt) { acc[mt][nt][0] = 0.f; acc[mt][nt][1] = 0.f; acc[mt][nt][2] = 0.f; acc[mt][nt][3] = 0.f; }
#pragma unroll
  for (int ks = 0; ks < 4; ++ks) {
    s16x8 b0 = *(const s16x8*)&Dt[lo][ks * 32 + hi * 8];
    s16x8 b1 = *(const s16x8*)&Dt[16 + lo][ks * 32 + hi * 8];
#pragma unroll
    for (int mt = 0; mt < 3; ++mt) {
      s16x8 a = *(const s16x8*)&wqkvb[(size_t)(w * 48 + mt * 16 + lo) * CC + ks * 32 + hi * 8];
      acc[mt][0] = __builtin_amdgcn_mfma_f32_16x16x32_bf16(a, b0, acc[mt][0], 0, 0, 0);
      acc[mt][1] = __builtin_amdgcn_mfma_f32_16x16x32_bf16(a, b1, acc[mt][1], 0, 0, 0);
    }
  }
#pragma unroll
  for (int mt = 0; mt < 3; ++mt)
#pragma unroll
    for (int nt = 0; nt < 2; ++nt) {
      int m0 = w * 48 + mt * 16 + hi * 4;
      int t = t0 + nt * 16 + lo;
      short4 pk;
      pk.x = f2bf(acc[mt][nt][0]); pk.y = f2bf(acc[mt][nt][1]);
      pk.z = f2bf(acc[mt][nt][2]); pk.w = f2bf(acc[mt][nt][3]);
      if (m0 < 64) {
        *(short4*)(q + ((size_t)b * TT + t) * DK + m0) = pk;
      } else if (m0 < 128) {
        *(short4*)(k + ((size_t)b * TT + t) * DK + (m0 - 64)) = pk;
      } else {
        int d = m0 - 128;
        vt[((size_t)b * DK + d) * TT + t] = pk.x;
        vt[((size_t)b * DK + d + 1) * TT + t] = pk.y;
        vt[((size_t)b * DK + d + 2) * TT + t] = pk.z;
        vt[((size_t)b * DK + d + 3) * TT + t] = pk.w;
      }
    }
}

// ---------------- flash attention, split-K: each block does TT/NSPLIT k-positions ----------------
__global__ __launch_bounds__(128) void k_attn(const short* __restrict__ qb,
                                              const short* __restrict__ kbuf,
                                              const short* __restrict__ vtb,
                                              const float* __restrict__ mask,
                                              float* __restrict__ pacc,
                                              float* __restrict__ pml) {
  int sp = blockIdx.x & (NSPLIT - 1);
  int qt = (blockIdx.x >> 2) & 31;
  int b = blockIdx.x >> 7;
  int w = threadIdx.x >> 6, lane = threadIdx.x & 63;
  int lo = lane & 15, hi = lane >> 4;

  __shared__ __align__(16) short ks[64][72];
  __shared__ __align__(16) short vt[64][72];
  __shared__ __align__(16) short ps[2][16][68];  // stride 68: hi*8 bank spread on writes
  __shared__ float ms[64];

  const short* qp = qb + ((size_t)b * TT + qt * 32 + w * 16 + lo) * DK + hi * 8;
  s16x8 aq0 = *(const s16x8*)qp;
  s16x8 aq1 = *(const s16x8*)(qp + 32);

  f32x4 acc[4];
  float m_i[4], l_i[4];
#pragma unroll
  for (int r = 0; r < 4; ++r) {
    m_i[r] = -3.0e38f; l_i[r] = 0.f;
#pragma unroll
    for (int nt = 0; nt < 4; ++nt) acc[nt][r] = 0.f;
  }
  const float scale = 0.125f;

  for (int kb2 = sp * (TT / 64 / NSPLIT); kb2 < (sp + 1) * (TT / 64 / NSPLIT); ++kb2) {
    __syncthreads();
    for (int i = threadIdx.x; i < 512; i += 128) {
      int r = i >> 3, ch = i & 7;
      *(s16x8*)&ks[r][ch * 8] =
          *(const s16x8*)(kbuf + ((size_t)b * TT + kb2 * 64 + r) * DK + ch * 8);
      *(s16x8*)&vt[r][ch * 8] =
          *(const s16x8*)(vtb + ((size_t)b * DK + r) * TT + kb2 * 64 + ch * 8);
    }
    if (threadIdx.x < 64) ms[threadIdx.x] = mask[(size_t)b * TT + kb2 * 64 + threadIdx.x];
    __syncthreads();

    f32x4 sc[4];
#pragma unroll
    for (int nt = 0; nt < 4; ++nt) {
      f32x4 z; z[0] = 0.f; z[1] = 0.f; z[2] = 0.f; z[3] = 0.f;
      s16x8 bk0 = *(const s16x8*)&ks[nt * 16 + lo][hi * 8];
      s16x8 bk1 = *(const s16x8*)&ks[nt * 16 + lo][32 + hi * 8];
      z = __builtin_amdgcn_mfma_f32_16x16x32_bf16(aq0, bk0, z, 0, 0, 0);
      z = __builtin_amdgcn_mfma_f32_16x16x32_bf16(aq1, bk1, z, 0, 0, 0);
      sc[nt] = z;
    }
#pragma unroll
    for (int nt = 0; nt < 4; ++nt) {
      float mv = ms[nt * 16 + lo];
      float addv = (1.f - mv) * -1e30f;
#pragma unroll
      for (int r = 0; r < 4; ++r) sc[nt][r] = sc[nt][r] * scale * mv + addv;
    }
    float alpha[4];
#pragma unroll
    for (int r = 0; r < 4; ++r) {
      float m0 = fmaxf(fmaxf(sc[0][r], sc[1][r]), fmaxf(sc[2][r], sc[3][r]));
#pragma unroll
      for (int off = 1; off < 16; off <<= 1) m0 = fmaxf(m0, __shfl_xor(m0, off));
      float mn = fmaxf(m_i[r], m0);
      alpha[r] = __expf(m_i[r] - mn);
      m_i[r] = mn;
    }
    float psum[4] = {0.f, 0.f, 0.f, 0.f};
#pragma unroll
    for (int nt = 0; nt < 4; ++nt)
#pragma unroll
      for (int r = 0; r < 4; ++r) {
        float p = __expf(sc[nt][r] - m_i[r]);
        psum[r] += p;
        ps[w][hi * 4 + r][nt * 16 + lo] = f2bf(p);
      }
#pragma unroll
    for (int r = 0; r < 4; ++r) {
      float sum = psum[r];
#pragma unroll
      for (int off = 1; off < 16; off <<= 1) sum += __shfl_xor(sum, off);
      l_i[r] = l_i[r] * alpha[r] + sum;
    }
#pragma unroll
    for (int nt = 0; nt < 4; ++nt)
#pragma unroll
      for (int r = 0; r < 4; ++r) acc[nt][r] *= alpha[r];

    s16x8 ap0 = *(const s16x8*)&ps[w][lo][hi * 8];
    s16x8 ap1 = *(const s16x8*)&ps[w][lo][32 + hi * 8];
#pragma unroll
    for (int nt = 0; nt < 4; ++nt) {
      s16x8 bv0 = *(const s16x8*)&vt[nt * 16 + lo][hi * 8];
      s16x8 bv1 = *(const s16x8*)&vt[nt * 16 + lo][32 + hi * 8];
      acc[nt] = __builtin_amdgcn_mfma_f32_16x16x32_bf16(ap0, bv0, acc[nt], 0, 0, 0);
      acc[nt] = __builtin_amdgcn_mfma_f32_16x16x32_bf16(ap1, bv1, acc[nt], 0, 0, 0);
    }
  }
  // write partials: pacc[b][row][split][d] fp32, pml[b][row][split][2]
#pragma unroll
  for (int r = 0; r < 4; ++r) {
    int row = qt * 32 + w * 16 + hi * 4 + r;
    size_t pb = (((size_t)b * TT + row) * NSPLIT + sp) * DK;
#pragma unroll
    for (int nt = 0; nt < 4; ++nt) pacc[pb + nt * 16 + lo] = acc[nt][r];
    if (lo == 0) {
      size_t mb = (((size_t)b * TT + row) * NSPLIT + sp) * 2;
      pml[mb] = m_i[r];
      pml[mb + 1] = l_i[r];
    }
  }
}

// ---------------- combine split-K partials -> bf16 head ----------------
__global__ __launch_bounds__(256) void k_attn_combine(const float* __restrict__ pacc,
                                                      const float* __restrict__ pml,
                                                      const float* __restrict__ mask,
                                                      short* __restrict__ head) {
  int tid = blockIdx.x * 256 + threadIdx.x;  // 65536 = BB*TT*4 chunks
  int chunk = tid & 3;
  int row = (tid >> 2) & (TT - 1);
  int b = tid >> 12;
  size_t rb = (size_t)b * TT + row;
  float m[NSPLIT], l[NSPLIT];
#pragma unroll
  for (int s = 0; s < NSPLIT; ++s) {
    m[s] = pml[(rb * NSPLIT + s) * 2];
    l[s] = pml[(rb * NSPLIT + s) * 2 + 1];
  }
  float M = fmaxf(fmaxf(m[0], m[1]), fmaxf(m[2], m[3]));
  float wgt[NSPLIT], L = 0.f;
#pragma unroll
  for (int s = 0; s < NSPLIT; ++s) { wgt[s] = __expf(m[s] - M); L += wgt[s] * l[s]; }
  float inv = mask[rb] / L;
  float o[16];
#pragma unroll
  for (int j = 0; j < 16; ++j) o[j] = 0.f;
#pragma unroll
  for (int s = 0; s < NSPLIT; ++s) {
    const float4* pa = (const float4*)(pacc + (rb * NSPLIT + s) * DK + chunk * 16);
#pragma unroll
    for (int j4 = 0; j4 < 4; ++j4) {
      float4 v = pa[j4];
      o[j4 * 4] += wgt[s] * v.x; o[j4 * 4 + 1] += wgt[s] * v.y;
      o[j4 * 4 + 2] += wgt[s] * v.z; o[j4 * 4 + 3] += wgt[s] * v.w;
    }
  }
  short h[16];
#pragma unroll
  for (int j = 0; j < 16; ++j) h[j] = f2bf(o[j] * inv);
  *(uint4*)(head + rb * DK + chunk * 16) = *(uint4*)h;
  *(uint4*)(head + rb * DK + chunk * 16 + 8) = *(uint4*)(h + 8);
}

// ---------------- heads@Wo2 (MFMA, K=64) + residual (+ partials) ----------------
__global__ __launch_bounds__(256) void k_attnout(const short* __restrict__ head,
                                                 const short* __restrict__ wo2b,
                                                 const float* __restrict__ res,
                                                 float* __restrict__ out,
                                                 float* __restrict__ part_out) {
  int tile = blockIdx.x & 31, b = blockIdx.x >> 5;
  int t0 = tile * 32;
  __shared__ __align__(16) short Ht[32][72];
  {
    int i = threadIdx.x;  // 256 = 32 rows x 8 chunks
    int t = i >> 3, ch = i & 7;
    *(s16x8*)&Ht[t][ch * 8] =
        *(const s16x8*)(head + ((size_t)b * TT + t0 + t) * DK + ch * 8);
  }
  __syncthreads();

  int w = threadIdx.x >> 6, lane = threadIdx.x & 63;
  int lo = lane & 15, hi = lane >> 4;
  f32x4 acc[2][2];
#pragma unroll
  for (int mt = 0; mt < 2; ++mt)
#pragma unroll
    for (int nt = 0; nt < 2; ++nt) { acc[mt][nt][0] = 0.f; acc[mt][nt][1] = 0.f; acc[mt][nt][2] = 0.f; acc[mt][nt][3] = 0.f; }
#pragma unroll
  for (int ks = 0; ks < 2; ++ks) {
    s16x8 b0 = *(const s16x8*)&Ht[lo][ks * 32 + hi * 8];
    s16x8 b1 = *(const s16x8*)&Ht[16 + lo][ks * 32 + hi * 8];
    s16x8 a0 = *(const s16x8*)&wo2b[(size_t)(w * 32 + lo) * DK + ks * 32 + hi * 8];
    s16x8 a1 = *(const s16x8*)&wo2b[(size_t)(w * 32 + 16 + lo) * DK + ks * 32 + hi * 8];
    acc[0][0] = __builtin_amdgcn_mfma_f32_16x16x32_bf16(a0, b0, acc[0][0], 0, 0, 0);
    acc[0][1] = __builtin_amdgcn_mfma_f32_16x16x32_bf16(a0, b1, acc[0][1], 0, 0, 0);
    acc[1][0] = __builtin_amdgcn_mfma_f32_16x16x32_bf16(a1, b0, acc[1][0], 0, 0, 0);
    acc[1][1] = __builtin_amdgcn_mfma_f32_16x16x32_bf16(a1, b1, acc[1][1], 0, 0, 0);
  }
  float s = 0.f, ss = 0.f;
#pragma unroll
  for (int mt = 0; mt < 2; ++mt)
#pragma unroll
    for (int nt = 0; nt < 2; ++nt)
#pragma unroll
      for (int r = 0; r < 4; ++r) {
        int row = w * 32 + mt * 16 + hi * 4 + r;
        int t = t0 + nt * 16 + lo;
        size_t idx = ((size_t)b * CC + row) * TT + t;
        float v = acc[mt][nt][r] + res[idx];
        out[idx] = v;
        s += v; ss += v * v;
      }
  block_partial_256(s, ss, part_out + (size_t)blockIdx.x * 2);
}

// ---------------- FC (LN fused in, MFMA) + relu + residual -> d_out ----------------
__global__ __launch_bounds__(256) void k_fc(const float* __restrict__ in,
                                            const float* __restrict__ lng,
                                            const float* __restrict__ lnb,
                                            const float* __restrict__ part_in,
                                            const short* __restrict__ fcwb,
                                            const float* __restrict__ fb,
                                            float* __restrict__ out) {
  int tile = blockIdx.x & 31, b = blockIdx.x >> 5;
  int t0 = tile * 32;
  __shared__ float stats[2];
  __shared__ __align__(16) short Dt[32][136];
  ln_stats_from_parts(part_in + (size_t)b * 64, 32, stats);
  float mu = stats[0], rs = stats[1];
  for (int i = threadIdx.x; i < CC * 32; i += 256) {
    int c = i >> 5, t = i & 31;
    float v = in[((size_t)b * CC + c) * TT + t0 + t];
    Dt[t][c] = f2bf((v - mu) * rs * lng[c * TT + t0 + t] + lnb[c * TT + t0 + t]);
  }
  __syncthreads();

  int w = threadIdx.x >> 6, lane = threadIdx.x & 63;
  int lo = lane & 15, hi = lane >> 4;
  f32x4 acc[2][2];
#pragma unroll
  for (int mt = 0; mt < 2; ++mt)
#pragma unroll
    for (int nt = 0; nt < 2; ++nt) { acc[mt][nt][0] = 0.f; acc[mt][nt][1] = 0.f; acc[mt][nt][2] = 0.f; acc[mt][nt][3] = 0.f; }
#pragma unroll
  for (int ks = 0; ks < 4; ++ks) {
    s16x8 b0 = *(const s16x8*)&Dt[lo][ks * 32 + hi * 8];
    s16x8 b1 = *(const s16x8*)&Dt[16 + lo][ks * 32 + hi * 8];
    s16x8 a0 = *(const s16x8*)&fcwb[(size_t)(w * 32 + lo) * CC + ks * 32 + hi * 8];
    s16x8 a1 = *(const s16x8*)&fcwb[(size_t)(w * 32 + 16 + lo) * CC + ks * 32 + hi * 8];
    acc[0][0] = __builtin_amdgcn_mfma_f32_16x16x32_bf16(a0, b0, acc[0][0], 0, 0, 0);
    acc[0][1] = __builtin_amdgcn_mfma_f32_16x16x32_bf16(a0, b1, acc[0][1], 0, 0, 0);
    acc[1][0] = __builtin_amdgcn_mfma_f32_16x16x32_bf16(a1, b0, acc[1][0], 0, 0, 0);
    acc[1][1] = __builtin_amdgcn_mfma_f32_16x16x32_bf16(a1, b1, acc[1][1], 0, 0, 0);
  }
#pragma unroll
  for (int mt = 0; mt < 2; ++mt)
#pragma unroll
    for (int nt = 0; nt < 2; ++nt)
#pragma unroll
      for (int r = 0; r < 4; ++r) {
        int row = w * 32 + mt * 16 + hi * 4 + r;
        int t = t0 + nt * 16 + lo;
        size_t idx = ((size_t)b * CC + row) * TT + t;
        float v = acc[mt][nt][r] + fb[row];
        v = v > 0.f ? v : 0.f;
        out[idx] = v + in[idx];
      }
}

extern "C" void kernel_launch(void* const* d_in, const int* in_sizes, int n_in,
                              void* d_out, int out_size, void* d_ws, size_t ws_size,
                              hipStream_t stream) {
  const float* x    = (const float*)d_in[0];
  const float* mask = (const float*)d_in[1];
  const float* dww  = (const float*)d_in[2];
  const float* dwb  = (const float*)d_in[3];
  const float* pww  = (const float*)d_in[4];
  const float* pwb  = (const float*)d_in[5];
  const float* n0g  = (const float*)d_in[6];
  const float* n0b  = (const float*)d_in[7];
  const float* nsg  = (const float*)d_in[8];
  const float* nsb  = (const float*)d_in[9];
  const float* neg_ = (const float*)d_in[10];
  const float* neb  = (const float*)d_in[11];
  const float* Wq   = (const float*)d_in[12];
  const float* Wk   = (const float*)d_in[13];
  const float* Wv   = (const float*)d_in[14];
  const float* Wo   = (const float*)d_in[15];
  const float* fcw  = (const float*)d_in[16];
  const float* fcb  = (const float*)d_in[17];
  float* out = (float*)d_out;

  float* W = (float*)d_ws;
  const size_t NBCT = (size_t)BB * CC * TT;
  const size_t NBTD = (size_t)BB * TT * DK;
  const size_t CT = (size_t)CC * TT;
  float* O     = W;
  float* S     = W + NBCT;
  float* PART0 = W + 2 * NBCT;       // 16*128 pairs
  float* PARTS = PART0 + 4096;       // 5 stages x 16*32 pairs
  float* PACC  = PARTS + 5 * 1024;   // BB*TT*NSPLIT*DK fp32 = 4M floats
  float* PML   = PACC + NBTD * NSPLIT;  // BB*TT*NSPLIT*2
  short* QB    = (short*)(PML + (size_t)BB * TT * NSPLIT * 2);
  short* KB    = QB + NBTD;
  short* VT    = KB + NBTD;
  short* HDB   = VT + NBTD;
  short* PWWB  = HDB + NBTD;         // 4*128*128
  short* WQKVB = PWWB + 65536;       // 192*128
  short* WO2B  = WQKVB + 24576;      // 128*64
  short* FCWB  = WO2B + 8192;        // 128*128

  k_prep<<<448, 256, 0, stream>>>(pww, Wq, Wk, Wv, Wo, fcw, PWWB, WQKVB, WO2B, FCWB);
  k_addpos<<<BB * CC, 256, 0, stream>>>(x, O, PART0);
  // iter0: input raw, residual = LN0(input)
  k_dsconv<false, true><<<BB * 32, 256, 0, stream>>>(
      O, n0g, n0b, PART0, 128, dww, dwb, PWWB, pwb, S, PARTS);
  k_dsconv<true, false><<<BB * 32, 256, 0, stream>>>(
      S, nsg + 0 * CT, nsb + 0 * CT, PARTS, 32,
      dww + 1 * CC * KK, dwb + 1 * CC, PWWB + 1 * CC * CC, pwb + 1 * CC, O, PARTS + 1024);
  k_dsconv<true, false><<<BB * 32, 256, 0, stream>>>(
      O, nsg + 1 * CT, nsb + 1 * CT, PARTS + 1024, 32,
      dww + 2 * CC * KK, dwb + 2 * CC, PWWB + 2 * CC * CC, pwb + 2 * CC, S, PARTS + 2048);
  k_dsconv<true, false><<<BB * 32, 256, 0, stream>>>(
      S, nsg + 2 * CT, nsb + 2 * CT, PARTS + 2048, 32,
      dww + 3 * CC * KK, dwb + 3 * CC, PWWB + 3 * CC * CC, pwb + 3 * CC, O, PARTS + 3072);
  // qkv: input = LN_3(O)
  k_qkv<<<BB * 32, 256, 0, stream>>>(O, nsg + 3 * CT, nsb + 3 * CT, PARTS + 3072,
                                     WQKVB, QB, KB, VT);
  k_attn<<<BB * 32 * NSPLIT, 128, 0, stream>>>(QB, KB, VT, mask, PACC, PML);
  k_attn_combine<<<BB * TT * 4 / 256, 256, 0, stream>>>(PACC, PML, mask, HDB);
  // attnout: residual = O raw
  k_attnout<<<BB * 32, 256, 0, stream>>>(HDB, WO2B, O, S, PARTS + 4096);
  // fc: input = LN_e(S), residual = S raw
  k_fc<<<BB * 32, 256, 0, stream>>>(S, neg_, neb, PARTS + 4096, FCWB, fcb, out);
}